// Round 1
// baseline (987.627 us; speedup 1.0000x reference)
//
#include <hip/hip_runtime.h>

#define BLK 256

// ---- degree count: cnt[dst[e]] += 1 ----
__global__ __launch_bounds__(BLK) void k_count(const int* __restrict__ dst, int E, int N,
                                               float* __restrict__ cnt) {
    int i = blockIdx.x * BLK + threadIdx.x;
    if (i < E) {
        int d = dst[i];
        if ((unsigned)d < (unsigned)N) atomicAdd(&cnt[d], 1.0f);
    }
}

// ---- dinv[i] = rsqrt(deg_edges + 1 self-loop) ----
__global__ __launch_bounds__(BLK) void k_dinv(float* __restrict__ cnt, int N) {
    int i = blockIdx.x * BLK + threadIdx.x;
    if (i < N) cnt[i] = rsqrtf(cnt[i] + 1.0f);
}

// ---- g1[i][j] = (x[i] @ W1)[j] * dinv[i]   (32 -> 16) ----
__global__ __launch_bounds__(BLK) void k_transform1(const float* __restrict__ x,
                                                    const float* __restrict__ W1,
                                                    const float* __restrict__ dinv,
                                                    float* __restrict__ g1, int N) {
    __shared__ float sW[32 * 16];
    for (int t = threadIdx.x; t < 512; t += BLK) sW[t] = W1[t];
    __syncthreads();
    int i = blockIdx.x * BLK + threadIdx.x;
    if (i >= N) return;
    float xr[32];
    const float4* xp = (const float4*)(x + (size_t)i * 32);
#pragma unroll
    for (int q = 0; q < 8; ++q) {
        float4 v = xp[q];
        xr[4*q] = v.x; xr[4*q+1] = v.y; xr[4*q+2] = v.z; xr[4*q+3] = v.w;
    }
    float di = dinv[i];
    float o[16];
#pragma unroll
    for (int j = 0; j < 16; ++j) {
        float a = 0.f;
#pragma unroll
        for (int k = 0; k < 32; ++k) a += xr[k] * sW[k * 16 + j];
        o[j] = a * di;
    }
    float4* gp = (float4*)(g1 + (size_t)i * 16);
#pragma unroll
    for (int q = 0; q < 4; ++q)
        gp[q] = make_float4(o[4*q], o[4*q+1], o[4*q+2], o[4*q+3]);
}

// ---- edge scatter: agg[dst[e]][f] += g[src[e]][f], F lanes per edge ----
template <int F>
__global__ __launch_bounds__(BLK) void k_edge_agg(const int* __restrict__ src,
                                                  const int* __restrict__ dst,
                                                  int E, int N,
                                                  const float* __restrict__ g,
                                                  float* __restrict__ agg) {
    size_t t = (size_t)blockIdx.x * BLK + threadIdx.x;
    int e = (int)(t / F);
    int f = (int)(t & (F - 1));
    if (e >= E) return;
    int s = src[e], d = dst[e];
    if ((unsigned)s >= (unsigned)N || (unsigned)d >= (unsigned)N) return;
    atomicAdd(&agg[(size_t)d * F + f], g[(size_t)s * F + f]);
}

// ---- layer-1 epilogue fused with layer-2 transform+prescale ----
// h1[j] = relu((agg1[i][j] + g1[i][j]) * dinv[i] + b1[j])
// g2[i][o] = (h1 @ W2)[o] * dinv[i]          (16 -> 8)
__global__ __launch_bounds__(BLK) void k_node1(const float* __restrict__ g1,
                                               const float* __restrict__ agg1,
                                               const float* __restrict__ dinv,
                                               const float* __restrict__ b1,
                                               const float* __restrict__ W2,
                                               float* __restrict__ g2, int N) {
    __shared__ float sW[16 * 8];
    __shared__ float sb[16];
    for (int t = threadIdx.x; t < 128; t += BLK) sW[t] = W2[t];
    if (threadIdx.x < 16) sb[threadIdx.x] = b1[threadIdx.x];
    __syncthreads();
    int i = blockIdx.x * BLK + threadIdx.x;
    if (i >= N) return;
    float di = dinv[i];
    const float4* gp = (const float4*)(g1 + (size_t)i * 16);
    const float4* ap = (const float4*)(agg1 + (size_t)i * 16);
    float h[16];
#pragma unroll
    for (int q = 0; q < 4; ++q) {
        float4 gv = gp[q], av = ap[q];
        h[4*q+0] = fmaxf((av.x + gv.x) * di + sb[4*q+0], 0.f);
        h[4*q+1] = fmaxf((av.y + gv.y) * di + sb[4*q+1], 0.f);
        h[4*q+2] = fmaxf((av.z + gv.z) * di + sb[4*q+2], 0.f);
        h[4*q+3] = fmaxf((av.w + gv.w) * di + sb[4*q+3], 0.f);
    }
    float o[8];
#pragma unroll
    for (int j = 0; j < 8; ++j) {
        float a = 0.f;
#pragma unroll
        for (int k = 0; k < 16; ++k) a += h[k] * sW[k * 8 + j];
        o[j] = a * di;
    }
    float4* op = (float4*)(g2 + (size_t)i * 8);
    op[0] = make_float4(o[0], o[1], o[2], o[3]);
    op[1] = make_float4(o[4], o[5], o[6], o[7]);
}

// ---- layer-2 epilogue fused with final linear ----
// h2[o] = relu((agg2[i][o] + g2[i][o]) * dinv[i] + b2[o])
// out[i][k] = (h2 @ Wfc)[k] + bfc[k]          (8 -> 4)
__global__ __launch_bounds__(BLK) void k_node2(const float* __restrict__ g2,
                                               const float* __restrict__ agg2,
                                               const float* __restrict__ dinv,
                                               const float* __restrict__ b2,
                                               const float* __restrict__ Wfc,
                                               const float* __restrict__ bfc,
                                               float* __restrict__ out, int N) {
    __shared__ float sW[8 * 4];
    __shared__ float sb2[8];
    __shared__ float sbf[4];
    if (threadIdx.x < 32) sW[threadIdx.x] = Wfc[threadIdx.x];
    if (threadIdx.x < 8) sb2[threadIdx.x] = b2[threadIdx.x];
    if (threadIdx.x < 4) sbf[threadIdx.x] = bfc[threadIdx.x];
    __syncthreads();
    int i = blockIdx.x * BLK + threadIdx.x;
    if (i >= N) return;
    float di = dinv[i];
    const float4* gp = (const float4*)(g2 + (size_t)i * 8);
    const float4* ap = (const float4*)(agg2 + (size_t)i * 8);
    float h[8];
#pragma unroll
    for (int q = 0; q < 2; ++q) {
        float4 gv = gp[q], av = ap[q];
        h[4*q+0] = fmaxf((av.x + gv.x) * di + sb2[4*q+0], 0.f);
        h[4*q+1] = fmaxf((av.y + gv.y) * di + sb2[4*q+1], 0.f);
        h[4*q+2] = fmaxf((av.z + gv.z) * di + sb2[4*q+2], 0.f);
        h[4*q+3] = fmaxf((av.w + gv.w) * di + sb2[4*q+3], 0.f);
    }
    float o[4];
#pragma unroll
    for (int k = 0; k < 4; ++k) {
        float a = sbf[k];
#pragma unroll
        for (int j = 0; j < 8; ++j) a += h[j] * sW[j * 4 + k];
        o[k] = a;
    }
    ((float4*)(out + (size_t)i * 4))[0] = make_float4(o[0], o[1], o[2], o[3]);
}

extern "C" void kernel_launch(void* const* d_in, const int* in_sizes, int n_in,
                              void* d_out, int out_size, void* d_ws, size_t ws_size,
                              hipStream_t stream) {
    const float* x   = (const float*)d_in[0];
    const int*   ei  = (const int*)d_in[1];
    const float* W1  = (const float*)d_in[2];
    const float* b1  = (const float*)d_in[3];
    const float* W2  = (const float*)d_in[4];
    const float* b2  = (const float*)d_in[5];
    const float* Wfc = (const float*)d_in[6];
    const float* bfc = (const float*)d_in[7];

    int N = in_sizes[0] / 32;
    int E = in_sizes[1] / 2;
    const int* src = ei;
    const int* dst = ei + (size_t)E;

    float* ws   = (float*)d_ws;
    float* dinv = ws;                         // N
    float* g1   = dinv + (size_t)N;           // 16N
    float* agg1 = g1 + (size_t)16 * N;        // 16N
    float* g2   = agg1 + (size_t)16 * N;      // 8N
    float* agg2 = g2 + (size_t)8 * N;         // 8N

    hipMemsetAsync(dinv, 0, (size_t)N * 4, stream);
    hipMemsetAsync(agg1, 0, (size_t)16 * N * 4, stream);
    hipMemsetAsync(agg2, 0, (size_t)8 * N * 4, stream);

    k_count<<<(E + BLK - 1) / BLK, BLK, 0, stream>>>(dst, E, N, dinv);
    k_dinv<<<(N + BLK - 1) / BLK, BLK, 0, stream>>>(dinv, N);
    k_transform1<<<(N + BLK - 1) / BLK, BLK, 0, stream>>>(x, W1, dinv, g1, N);

    {
        size_t tot = (size_t)E * 16;
        k_edge_agg<16><<<(unsigned)((tot + BLK - 1) / BLK), BLK, 0, stream>>>(src, dst, E, N, g1, agg1);
    }
    k_node1<<<(N + BLK - 1) / BLK, BLK, 0, stream>>>(g1, agg1, dinv, b1, W2, g2, N);
    {
        size_t tot = (size_t)E * 8;
        k_edge_agg<8><<<(unsigned)((tot + BLK - 1) / BLK), BLK, 0, stream>>>(src, dst, E, N, g2, agg2);
    }
    k_node2<<<(N + BLK - 1) / BLK, BLK, 0, stream>>>(g2, agg2, dinv, b2, Wfc, bfc, (float*)d_out, N);
}